// Round 6
// baseline (9827.609 us; speedup 1.0000x reference)
//
#include <hip/hip_runtime.h>

typedef __attribute__((ext_vector_type(8))) short bf16x8;
typedef __attribute__((ext_vector_type(4))) float f32x4;
typedef __attribute__((ext_vector_type(4))) int i32x4;

#define Tn 1024
#define Bn 64
#define Hn 2048
#define NBLK 256
#define NTHR 512

// R18: FOUR independent rings (batch rows never mix in a GRU). Ring R owns
// batch rows [16R, 16R+16); within a ring, 64 col-blocks of 32 columns.
// blockIdx.x -> R = bid & 3, c = bid >> 2 (rings interleave across XCDs).
// WHY: the h-broadcast is MALL-BW-bound (~7.5 TB/s plateau across R16/R17).
// Read volume = 256KB x (2048/cols_per_block) per step; cols 16->32 halves
// it: 32MB -> 16MB/step.
//
// Dataflow ready counters: one line per (ring, consumer-leaf, K-slice-group).
// 4 rings x 8 leaves x 8 groups = 256 counters, each on its own 128B line
// (32 KB ctrl). Counter (R, leaf, g): bumped by the 8 producer col-blocks of
// group g in ring R (c>>3 == g), twice each (waves 0 and 1 after their own
// store drains); value == 16*(t+1) means ring R's h_{t+1} slice g is at MALL.
// Consumers: wave w of col-block c polls (R, c>>3, w) -> 8 pollers/line
// (R12 lesson: >100 RMW pollers on ONE line serialize; 8 is proven).
#define GRP(ring, leaf, g) (((((ring) << 6) | ((leaf) << 3) | (g))) * 32)

// watchdog: bounded spin so a liveness bug degrades to a wrong answer
// (diagnosable absmax failure) instead of a container-killing hang
#define SPIN_LIMIT (1u << 25)

__device__ __forceinline__ unsigned short f2b(float x) {
    // fp32 -> bf16 round-to-nearest-even
    unsigned u = __float_as_uint(x);
    return (unsigned short)((u + 0x7fffu + ((u >> 16) & 1u)) >> 16);
}
__device__ __forceinline__ float sigm(float x) {
    return __builtin_amdgcn_rcpf(1.0f + __expf(-x));
}
__device__ __forceinline__ float tanh_f(float x) {
    float e = __expf(2.0f * x);
    return 1.0f - 2.0f * __builtin_amdgcn_rcpf(1.0f + e);
}

// write-through system-scope stores: at MALL once vmcnt retires
__device__ __forceinline__ void store_short_wt(unsigned short* p, unsigned v) {
    asm volatile("global_store_short %0, %1, off sc0 sc1" :: "v"(p), "v"(v) : "memory");
}
__device__ __forceinline__ void store_dword_wt(float* p, float v) {
    asm volatile("global_store_dword %0, %1, off sc0 sc1" :: "v"(p), "v"(__float_as_uint(v)) : "memory");
}
__device__ __forceinline__ void store_u64_wt(unsigned long long* p, unsigned long long v) {
    asm volatile("global_store_dwordx2 %0, %1, off sc0 sc1" :: "v"(p), "v"(v) : "memory");
}
// Poll via atomic RMW(+0): the ONLY read primitive proven promptly coherent
// cross-XCD for ATOMICALLY-updated lines (R1-R6 ablation). asm because
// InstCombine turns fetch_add(p,0) back into a plain atomic load.
__device__ __forceinline__ unsigned poll_read(unsigned* p) {
    unsigned old;
    asm volatile("global_atomic_add %0, %1, %2, off sc0 sc1\n\ts_waitcnt vmcnt(0)"
                 : "=v"(old) : "v"(p), "v"(0u) : "memory");
    return old;
}

// h fragment layout (GLOBAL, shared by all rings; ring R touches only its
// mt==R stripes): h_f[kk][mt][laneF][e], kk=k>>5, mt=b>>4,
// laneF=((k>>3)&3)*16+(b&15), e=k&7. One MFMA A-frag = 64 lanes x 16B contig.
__device__ __forceinline__ long hfrag_off(int b, int k) {
    return ((long)(((k >> 5) * 4 + (b >> 4)) * 64) + ((k >> 3) & 3) * 16 + (b & 15)) * 8 + (k & 7);
}

// Prep: init_hidden fp32 -> bf16 h0 (frag layout, WT stores so the MALL copy
// is authoritative for gru's bypass loads); zero ready counters (WT too).
__global__ void prep_kernel(const float* __restrict__ init_h,
                            unsigned short* __restrict__ h0,
                            unsigned* __restrict__ ctrl) {
    const int i = blockIdx.x * 256 + threadIdx.x;  // 0..32767
    const int b  = i >> 9;
    const int k4 = (i & 511) << 2;
    float4 v = *reinterpret_cast<const float4*>(init_h + (long)b * Hn + k4);
    unsigned long long q = (unsigned long long)f2b(v.x)
                         | ((unsigned long long)f2b(v.y) << 16)
                         | ((unsigned long long)f2b(v.z) << 32)
                         | ((unsigned long long)f2b(v.w) << 48);
    store_u64_wt((unsigned long long*)(h0 + hfrag_off(b, k4)), q);
    if (i < 8192)
        asm volatile("global_store_dword %0, %1, off sc0 sc1"
                     :: "v"(ctrl + i), "v"(0u) : "memory");
}

// Persistent GRU. 256 blocks x 512 threads (8 waves) = 1 block/CU (at 256
// VGPR/wave a CU holds exactly one 8-wave block -> co-residency guaranteed).
// Ring R (bid&3) owns batch rows [16R,16R+16); col-block c (bid>>2) owns 32
// hidden units j in [32c, 32c+32). Wave w owns K-slice [256w, 256w+256);
// W rows for BOTH 16-col n-tiles live in REGISTERS (Bf[3][2][8] = 192 VGPR).
//
// Ledger: R13 dataflow flags (-11%). R14 REVERTED (x loads pre-poll; batched
//   LDS reduce). R15 setprio null (kept). R16 2-ring split (-23%).
//   R17 parity-red / 2-barrier / per-wave bump: null -> kept (simpler), and
//   its null + the 7.5TB/s plateau identified the MALL-BW bound that this
//   round attacks (read volume halves: 32->16MB/step).
//
// Register diet (stay under the 256/wave cliff; spills in hot loop are
// R12-class disasters):
//  - Bf 192 (irreducible: 3 gates x 2 n-tiles x 8 kk).
//  - hb[4] with TWO 4-load sub-bursts (16 regs not 32); sched_barrier(0)
//    between sub-burst 1's MFMAs and sub-burst 2's loads pins the reuse.
//  - x inputs staged through LDS by wave 2 (parity-duplexed xs[2][16][3]):
//    epilogue waves read xs AFTER sync_b -> no xv regs live across MFMA.
//    Race-free: wave2 writes xs[p] at t+2 only after sync_b(t+1), which is
//    after waves 0-1 finished reading xs[p] at t's epilogue.
//  - epilogue w_ih/bias constants reloaded EVERY step after sync_b (L2-hit
//    ~200cy, hidden under the 12 LDS sum reads) instead of 15 live regs.
//
// Buffer-reuse safety (per ring, R17 proof carries): every wave's h_t loads
// complete (vmcnt0, asm-tied) before sync_a(t); bumps(t) after sync_b(t);
// a producer stores h_{t+2} only after its 8 waves detect 16(t+1), which
// needs EVERY producer block's bumps(t) -> transitively after every
// consumer's h_t loads. Skew < 2 steps, deadlock-free.
//
// NO fences / cache maintenance in the hot loop (R5). All signals via RMW,
// all polls via RMW(+0).
__global__ void __launch_bounds__(NTHR, 2) gru_kernel(
    const float* __restrict__ inp,     // [T][B][3]
    const float* __restrict__ init_h,  // [B][H]
    const float* __restrict__ w_ih,    // [3H][3]
    const float* __restrict__ w_hh,    // [3H][H] fp32
    const float* __restrict__ bias,    // [3H]
    const float* __restrict__ bias_n,  // [H]
    unsigned short* __restrict__ h0,   // [B][H] bf16 frag-layout double buffer
    unsigned short* __restrict__ h1,
    unsigned* __restrict__ ctrl,       // [8192] ready counters (256 lines)
    float* __restrict__ out)           // [T][B]
{
    __shared__ f32x4 red[2][4][2][3][64];  // [parity][bucket][nt][gate][lane] = 48 KB
    __shared__ float xs[2][16][3];         // [parity][ring-row][input] x-stage

    const int tid  = threadIdx.x;
    const int lane = tid & 63;
    const int w    = tid >> 6;      // wave id = K-slice owner
    const int quad = lane >> 4;
    const int n16  = lane & 15;
    const int R    = blockIdx.x & 3;        // ring id (batch quarter)
    const int c    = blockIdx.x >> 2;       // col-block id 0..63
    const int ks   = w * 256;
    const int bbase = 16 * R;       // ring's batch base

    // ---- preload W rows into registers as bf16 B-fragments (one-time) ----
    // Bf[gate][ntile][kk]: col j = 32c + 16*ntile + n16, K cols ks+kk*32+quad*8
    bf16x8 Bf[3][2][8];
    #pragma unroll
    for (int g = 0; g < 3; ++g) {
        #pragma unroll
        for (int nt = 0; nt < 2; ++nt) {
            const long row = (long)(g * Hn + c * 32 + nt * 16 + n16);
            #pragma unroll
            for (int k = 0; k < 8; ++k) {
                const float* p = w_hh + row * Hn + ks + k * 32 + quad * 8;
                bf16x8 b;
                #pragma unroll
                for (int j = 0; j < 8; ++j) b[j] = (short)f2b(p[j]);
                Bf[g][nt][k] = b;
            }
        }
    }

    // fp32 hidden state (waves 0-1; rows bbase+quad*4+r, col jg=32c+16w+n16)
    float hst[4];
    if (w < 2) {
        const int jg = c * 32 + 16 * w + n16;
        #pragma unroll
        for (int r = 0; r < 4; ++r)
            hst[r] = init_h[(long)(bbase + quad * 4 + r) * Hn + jg];
    }

    const int leafC = c >> 3;          // consumer replica index (per ring)
    const int grp   = c >> 3;          // K-slice group we produce (per ring)

    for (int t = 0; t < Tn; ++t) {
        const unsigned short* hcur = (t & 1) ? h1 : h0;
        unsigned short* hnext      = (t & 1) ? h0 : h1;
        f32x4 (*redp)[2][3][64] = red[t & 1];   // parity LDS buffer

        // ---- x-stage: wave 2 loads inp[t] rows for this ring into LDS
        // (cached loads, pre-poll so HBM RTT hides under the poll's RTT;
        // epilogue waves read xs AFTER sync_b -> zero regs across MFMA) ----
        if (w == 2 && lane < 48) {
            const int row = lane / 3, col = lane % 3;
            xs[t & 1][row][col] = inp[((long)t * Bn + bbase + row) * 3 + col];
        }

        f32x4 acc[2][3];
        #pragma unroll
        for (int nt = 0; nt < 2; ++nt)
            #pragma unroll
            for (int g = 0; g < 3; ++g)
                acc[nt][g] = f32x4{0.f, 0.f, 0.f, 0.f};

        // ---- dataflow wait: THIS wave's K-slice (this ring) at MALL? ----
        // lane 0 spins, wave reconverges; volatile-asm ordering keeps the
        // h-burst loads below from hoisting above the poll. Target 16t:
        // 8 producer blocks x 2 per-wave bumps per step.
        if (lane == 0 && t) {
            const unsigned tgt = (unsigned)(t << 4);   // 16*t
            unsigned spins = 0;
            while (poll_read(&ctrl[GRP(R, leafC, w)]) < tgt) {
                __builtin_amdgcn_s_sleep(1);
                if (++spins > SPIN_LIMIT) break;   // watchdog
            }
        }

        // wave's A-frag base: frag f = (8w+kki)*4 + R at short-offset
        // f*512 + lane*8; kki stride = 4*512 = 2048 shorts.
        const unsigned short* pa = hcur + ((long)((32 * w + R) * 64 + lane)) * 8;

        // ---- 2 sub-bursts of 4x dwordx4 loads (hb reg reuse), 24 MFMAs each
        i32x4 hb[4];
        #pragma unroll
        for (int half = 0; half < 2; ++half) {
            #pragma unroll
            for (int f = 0; f < 4; ++f) {
                const int kki = half * 4 + f;
                asm volatile("global_load_dwordx4 %0, %1, off sc0 sc1"
                             : "=v"(hb[f]) : "v"(pa + (long)kki * 2048) : "memory");
            }
            asm volatile("s_waitcnt vmcnt(0)"
                         : "+v"(hb[0]), "+v"(hb[1]), "+v"(hb[2]), "+v"(hb[3])
                         :: "memory");
            __builtin_amdgcn_s_setprio(1);
            #pragma unroll
            for (int f = 0; f < 4; ++f) {
                const int kki = half * 4 + f;
                union { i32x4 q; bf16x8 v; } u;
                u.q = hb[f];
                bf16x8 a = u.v;
                #pragma unroll
                for (int nt = 0; nt < 2; ++nt) {
                    acc[nt][0] = __builtin_amdgcn_mfma_f32_16x16x32_bf16(a, Bf[0][nt][kki], acc[nt][0], 0, 0, 0);
                    acc[nt][1] = __builtin_amdgcn_mfma_f32_16x16x32_bf16(a, Bf[1][nt][kki], acc[nt][1], 0, 0, 0);
                    acc[nt][2] = __builtin_amdgcn_mfma_f32_16x16x32_bf16(a, Bf[2][nt][kki], acc[nt][2], 0, 0, 0);
                }
            }
            __builtin_amdgcn_s_setprio(0);
            // pin sub-burst 2's loads BELOW sub-burst 1's MFMAs so hb[] is
            // physically reused (16 regs, not 32).
            __builtin_amdgcn_sched_barrier(0);
        }

        // ---- cross-wave K reduction through parity LDS (2 barriers) ----
        // Round 1: waves 4-7 publish into bucket (w-4) of THIS parity.
        if (w >= 4) {
            #pragma unroll
            for (int nt = 0; nt < 2; ++nt)
                #pragma unroll
                for (int g = 0; g < 3; ++g)
                    redp[w - 4][nt][g][lane] = acc[nt][g];
        }
        __syncthreads();   // sync_a
        // Round 2 (waves 0-3): wave-local bucket w. BATCHED: 6 reads first,
        // then 6 add+writes (R14 lesson: per-element interleave serializes).
        if (w < 4) {
            f32x4 tmp[2][3];
            #pragma unroll
            for (int nt = 0; nt < 2; ++nt)
                #pragma unroll
                for (int g = 0; g < 3; ++g)
                    tmp[nt][g] = redp[w][nt][g][lane];
            #pragma unroll
            for (int nt = 0; nt < 2; ++nt)
                #pragma unroll
                for (int g = 0; g < 3; ++g)
                    redp[w][nt][g][lane] = acc[nt][g] + tmp[nt][g];
        }
        __syncthreads();   // sync_b  (waves 2-7 run ahead into t+1)

        if (w < 2) {
            // epilogue constants: per-step cached reloads (L2-resident,
            // issued first so their latency hides under the LDS sum reads)
            const int jg = c * 32 + 16 * w + n16;
            float wr0 = w_ih[jg*3+0], wr1 = w_ih[jg*3+1], wr2 = w_ih[jg*3+2];
            float wz0 = w_ih[(Hn+jg)*3+0], wz1 = w_ih[(Hn+jg)*3+1], wz2 = w_ih[(Hn+jg)*3+2];
            float wn0 = w_ih[(2*Hn+jg)*3+0], wn1 = w_ih[(2*Hn+jg)*3+1], wn2 = w_ih[(2*Hn+jg)*3+2];
            float br_ = bias[jg], bz_ = bias[Hn+jg], bn2_ = bias[2*Hn+jg];
            float bnn_ = bias_n[jg];

            // wave We sums n-tile We over the 4 buckets (12 LDS reads)
            f32x4 s0 = redp[0][w][0][lane], s1 = redp[0][w][1][lane], s2 = redp[0][w][2][lane];
            #pragma unroll
            for (int src = 1; src < 4; ++src) {
                s0 += redp[src][w][0][lane];
                s1 += redp[src][w][1][lane];
                s2 += redp[src][w][2][lane];
            }
            // x inputs from the LDS stage
            float xv[4][3];
            #pragma unroll
            for (int r = 0; r < 4; ++r) {
                xv[r][0] = xs[t & 1][quad * 4 + r][0];
                xv[r][1] = xs[t & 1][quad * 4 + r][1];
                xv[r][2] = xs[t & 1][quad * 4 + r][2];
            }
            #pragma unroll
            for (int r = 0; r < 4; ++r) {
                const int b = bbase + quad * 4 + r;
                float pr = br_ + wr0*xv[r][0] + wr1*xv[r][1] + wr2*xv[r][2] + s0[r];
                float pz = bz_ + wz0*xv[r][0] + wz1*xv[r][1] + wz2*xv[r][2] + s1[r];
                float rr = sigm(pr);
                float zz = sigm(pz);
                float pn = bn2_ + wn0*xv[r][0] + wn1*xv[r][1] + wn2*xv[r][2] + rr * (s2[r] + bnn_);
                float nn = tanh_f(pn);
                float hv = nn + zz * (hst[r] - nn);
                hst[r] = hv;
                // frag store: j=32c+16w+n16 -> kk=c, laneF=(2w+(n16>>3))*16
                // + quad*4+r, e=n16&7, mt=R
                store_short_wt(hnext + ((long)((c * 4 + R) * 64)
                                        + (2 * w + (n16 >> 3)) * 16 + quad * 4 + r) * 8 + (n16 & 7),
                               (unsigned)f2b(hv));
                if (w == 0 && c == 0 && n16 == 0)
                    store_dword_wt(out + t * Bn + b, hv);
            }
            // ---- per-wave producer signal: drain OWN stores, then bump the
            // 8 leaf replicas of our group's counter (8 lanes, one atomic
            // instr, 8 distinct lines). No block-wide rendezvous.
            asm volatile("s_waitcnt vmcnt(0)" ::: "memory");  // stores at MALL
            if (lane < 8)
                __hip_atomic_fetch_add(&ctrl[GRP(R, lane, grp)], 1u,
                                       __ATOMIC_RELAXED, __HIP_MEMORY_SCOPE_SYSTEM);
        }
        // no loop-end barrier: red[] parity removes the WAR hazard; xs[] is
        // parity-duplexed; h-buffer reuse is ordered through the flag
        // protocol (see header proof).
    }
}

extern "C" void kernel_launch(void* const* d_in, const int* in_sizes, int n_in,
                              void* d_out, int out_size, void* d_ws, size_t ws_size,
                              hipStream_t stream) {
    const float* inp    = (const float*)d_in[0];  // [1024][64][3]
    const float* init_h = (const float*)d_in[1];  // [64][2048]
    const float* w_ih   = (const float*)d_in[2];  // [6144][3]
    const float* w_hh   = (const float*)d_in[3];  // [6144][2048]
    const float* bias   = (const float*)d_in[4];  // [6144]
    const float* bias_n = (const float*)d_in[5];  // [2048]
    float* out = (float*)d_out;                   // [1024][64]

    unsigned short* h0 = (unsigned short*)d_ws;          // 262144 B
    unsigned short* h1 = h0 + 131072L;                   // 262144 B
    unsigned* ctrl     = (unsigned*)(h1 + 131072L);      // 32768 B

    prep_kernel<<<128, 256, 0, stream>>>(init_h, h0, ctrl);
    gru_kernel<<<NBLK, NTHR, 0, stream>>>(inp, init_h, w_ih, w_hh, bias, bias_n,
                                          h0, h1, ctrl, out);
}

// Round 7
// 4114.653 us; speedup vs baseline: 2.3884x; 2.3884x over previous
//
#include <hip/hip_runtime.h>

typedef __attribute__((ext_vector_type(8))) short bf16x8;
typedef __attribute__((ext_vector_type(4))) float f32x4;
typedef __attribute__((ext_vector_type(4))) int i32x4;

#define Tn 1024
#define Bn 64
#define Hn 2048
#define NBLK 256
#define NTHR 512

// R16 geometry (PROVEN, 4337us): TWO independent rings (batch rows never mix
// in a GRU). Ring R owns batch rows [32R, 32R+32); 128 col-blocks of 16 cols
// per ring. blockIdx.x -> R = bid & 1, c = bid >> 1.
//
// REGISTER WALL (R18 lesson): with 8-wave blocks (2 waves/SIMD), unified
// VGPR+AGPR budget is 256/wave (512-reg file per SIMD / 2). Bf regs =
// 3*cols*K_per_wave/128; at 16 cols, K=256 -> 96 ✓. At 32 cols -> 192 ->
// total ~270 -> compiler clamps to 128 arch + AGPR + SCRATCH SPILL
// (R18: WRITE_SIZE 2.1x, dur 2.26x). Col-blocks >16 need 4-wave/512-reg
// blocks (1 wave/SIMD) w/ mixed AGPR Bf -- deferred, high risk.
//
// Dataflow ready counters: one line per (ring, consumer-leaf, K-slice-group).
// 2 rings x 16 leaves x 8 groups = 256 counters, each on its own 128B line
// (32 KB ctrl). Replica (R, leaf, g) is bumped once per step by each of the
// 16 producer col-blocks of group g in ring R (c>>4 == g); value == 16*(t+1)
// means ring R's h_{t+1} slice g is fully at MALL. Consumers: wave w of
// col-block c polls (R, c>>3, w) -> 8 pollers/line (R12 lesson: >100 RMW
// pollers on ONE line serialize, so replicate per leaf).
#define GRP(ring, leaf, g) (((((ring) << 7) | ((leaf) << 3) | (g))) * 32)

// watchdog: bounded spin so a liveness bug degrades to a wrong answer
// (diagnosable absmax failure) instead of a container-killing hang
#define SPIN_LIMIT (1u << 25)

__device__ __forceinline__ unsigned short f2b(float x) {
    // fp32 -> bf16 round-to-nearest-even
    unsigned u = __float_as_uint(x);
    return (unsigned short)((u + 0x7fffu + ((u >> 16) & 1u)) >> 16);
}
__device__ __forceinline__ float sigm(float x) {
    return __builtin_amdgcn_rcpf(1.0f + __expf(-x));
}
__device__ __forceinline__ float tanh_f(float x) {
    float e = __expf(2.0f * x);
    return 1.0f - 2.0f * __builtin_amdgcn_rcpf(1.0f + e);
}

// write-through system-scope stores: at MALL once vmcnt retires
__device__ __forceinline__ void store_short_wt(unsigned short* p, unsigned v) {
    asm volatile("global_store_short %0, %1, off sc0 sc1" :: "v"(p), "v"(v) : "memory");
}
__device__ __forceinline__ void store_dword_wt(float* p, float v) {
    asm volatile("global_store_dword %0, %1, off sc0 sc1" :: "v"(p), "v"(__float_as_uint(v)) : "memory");
}
__device__ __forceinline__ void store_u64_wt(unsigned long long* p, unsigned long long v) {
    asm volatile("global_store_dwordx2 %0, %1, off sc0 sc1" :: "v"(p), "v"(v) : "memory");
}
// Poll via atomic RMW(+0): the ONLY read primitive proven promptly coherent
// cross-XCD for ATOMICALLY-updated lines (R1-R6 ablation). asm because
// InstCombine turns fetch_add(p,0) back into a plain atomic load.
__device__ __forceinline__ unsigned poll_read(unsigned* p) {
    unsigned old;
    asm volatile("global_atomic_add %0, %1, %2, off sc0 sc1\n\ts_waitcnt vmcnt(0)"
                 : "=v"(old) : "v"(p), "v"(0u) : "memory");
    return old;
}

// h fragment layout (GLOBAL, shared by both rings; each ring touches only its
// own mt stripes): h_f[kk][mt][laneF][e], kk=k>>5, mt=b>>4,
// laneF=((k>>3)&3)*16+(b&15), e=k&7. One MFMA A-frag = 64 lanes x 16B contig.
__device__ __forceinline__ long hfrag_off(int b, int k) {
    return ((long)(((k >> 5) * 4 + (b >> 4)) * 64) + ((k >> 3) & 3) * 16 + (b & 15)) * 8 + (k & 7);
}

// Prep: init_hidden fp32 -> bf16 h0 (frag layout, WT stores so the MALL copy
// is authoritative for gru's bypass loads); zero ready counters (WT too).
__global__ void prep_kernel(const float* __restrict__ init_h,
                            unsigned short* __restrict__ h0,
                            unsigned* __restrict__ ctrl) {
    const int i = blockIdx.x * 256 + threadIdx.x;  // 0..32767
    const int b  = i >> 9;
    const int k4 = (i & 511) << 2;
    float4 v = *reinterpret_cast<const float4*>(init_h + (long)b * Hn + k4);
    unsigned long long q = (unsigned long long)f2b(v.x)
                         | ((unsigned long long)f2b(v.y) << 16)
                         | ((unsigned long long)f2b(v.z) << 32)
                         | ((unsigned long long)f2b(v.w) << 48);
    store_u64_wt((unsigned long long*)(h0 + hfrag_off(b, k4)), q);
    if (i < 8192)
        asm volatile("global_store_dword %0, %1, off sc0 sc1"
                     :: "v"(ctrl + i), "v"(0u) : "memory");
}

// Persistent GRU. 256 blocks x 512 threads (8 waves) = 1 block/CU, all CUs.
// Ring R (bid&1) owns batch rows [32R,32R+32); col-block c (bid>>1) owns 16
// hidden units j in [16c, 16c+16). Wave w owns K-slice [256w, 256w+256);
// W rows live in REGISTERS (Bf[3][8] = 96 VGPRs).
//
// Ledger: R13 dataflow flags (-11%). R14 REVERTED (x loads stay BEFORE the
//   poll -- their RTT hides under the poll's own atomic RTT; LDS reduce
//   stays batched-read/batched-write with barriers). R15 setprio: null,
//   kept. R16 batch-split 2 rings + one 16-load burst (-23%, 4337us).
//   R17 parity-red/2-barrier/per-wave-bump: null -> structure reverted to
//   R16's simpler 4-barrier form. R18 32-col blocks: -126% (register wall:
//   Bf 192 regs > 256 unified budget -> scratch spill; 4-deep sub-bursts
//   crippled MLP) -- REVERTED.
// R19 (this): counted-vmcnt split of the single 16-load burst. All 16 loads
//   issue back-to-back (full MLP), then vmcnt(8) releases frags 0-7 for the
//   first 24 MFMAs while frags 8-15 remain in flight; vmcnt(0) before the
//   last 24. vmcnt retires in ISSUE ORDER (m135), so vmcnt(8) leaves exactly
//   the newest 8 (hb[8..15]) outstanding regardless of any pre-poll x-loads
//   still pending at t=0. MFMA<->waitcnt ordering is enforced by the "+v"
//   dataflow ties (proven mechanism of this kernel).
//   DIAGNOSTIC: a win => load phase had exposed latency; a null => the
//   7.5 TB/s MALL plateau is a true BW ceiling -> volume halving (4-wave/
//   512-reg design) is the justified next step.
//
// Buffer-reuse safety: a block stores h_{t+2} only after its 8 waves saw all
// counters at 16(t+1), i.e. after EVERY producer of its ring stored h_{t+1},
// which (program order + drain) is after those blocks finished READING h_t
// -> the double buffer never races. Skew < 2 steps, deadlock-free (all 256
// blocks co-resident: 1 block/CU, 24KB LDS, 8 waves, 128 VGPR).
//
// TWO-ROUND LDS reduction (24 KB). NO fences / cache maintenance in the hot
// loop (R5). All signals via RMW, all polls via RMW(+0).
__global__ void __launch_bounds__(NTHR, 2) gru_kernel(
    const float* __restrict__ inp,     // [T][B][3]
    const float* __restrict__ init_h,  // [B][H]
    const float* __restrict__ w_ih,    // [3H][3]
    const float* __restrict__ w_hh,    // [3H][H] fp32
    const float* __restrict__ bias,    // [3H]
    const float* __restrict__ bias_n,  // [H]
    unsigned short* __restrict__ h0,   // [B][H] bf16 frag-layout double buffer
    unsigned short* __restrict__ h1,
    unsigned* __restrict__ ctrl,       // [8192] ready counters (256 lines)
    float* __restrict__ out)           // [T][B]
{
    __shared__ f32x4 red[4][2][3][64];  // [bucket][m][nt][lane] = 24 KB

    const int tid  = threadIdx.x;
    const int lane = tid & 63;
    const int w    = tid >> 6;      // wave id = K-slice owner
    const int quad = lane >> 4;
    const int n16  = lane & 15;
    const int R    = blockIdx.x & 1;        // ring id (batch half)
    const int c    = blockIdx.x >> 1;       // col-block id 0..127
    const int jg   = c * 16 + n16;  // this lane's hidden column (epilogue)
    const int ks   = w * 256;
    const int bbase = 32 * R;       // ring's batch base

    // ---- preload W rows into registers as bf16 B-fragments (one-time) ----
    bf16x8 Bf[3][8];
    #pragma unroll
    for (int nt = 0; nt < 3; ++nt) {
        const long row = (long)(nt * Hn + jg);
        #pragma unroll
        for (int k = 0; k < 8; ++k) {
            const float* p = w_hh + row * Hn + ks + k * 32 + quad * 8;
            bf16x8 b;
            #pragma unroll
            for (int j = 0; j < 8; ++j) b[j] = (short)f2b(p[j]);
            Bf[nt][k] = b;
        }
    }

    // Epilogue constants (used by waves 0-1; all 64 lanes active)
    float wr0 = w_ih[jg*3+0], wr1 = w_ih[jg*3+1], wr2 = w_ih[jg*3+2];
    float wz0 = w_ih[(Hn+jg)*3+0], wz1 = w_ih[(Hn+jg)*3+1], wz2 = w_ih[(Hn+jg)*3+2];
    float wn0 = w_ih[(2*Hn+jg)*3+0], wn1 = w_ih[(2*Hn+jg)*3+1], wn2 = w_ih[(2*Hn+jg)*3+2];
    float br_ = bias[jg], bz_ = bias[Hn+jg], bn2_ = bias[2*Hn+jg];
    float bnn_ = bias_n[jg];

    // fp32 hidden state (waves 0-1; batch b = bbase + 16w + quad*4 + r, col jg)
    float hst[4];
    if (w < 2) {
        #pragma unroll
        for (int r = 0; r < 4; ++r)
            hst[r] = init_h[(long)(bbase + 16 * w + quad * 4 + r) * Hn + jg];
    }

    // epilogue frag-store decomposition of j = 16c + n16 (mt = 2R + w)
    const int kkE = c >> 1;                     // j>>5 (lane-uniform)
    const int qE  = (c & 1) * 2 + (n16 >> 3);
    const int eE  = n16 & 7;

    const int leafC = c >> 3;          // consumer replica index (per ring)
    const int grp   = c >> 4;          // K-slice group we produce (per ring)

    for (int t = 0; t < Tn; ++t) {
        const unsigned short* hcur = (t & 1) ? h1 : h0;
        unsigned short* hnext      = (t & 1) ? h0 : h1;

        // input contributions for this step. Issued BEFORE the poll: their
        // HBM/MALL RTT hides entirely under the poll's own atomic RTT
        // (R14 lesson: any other placement puts them on the critical path).
        float xv[4][3];
        if (w < 2) {
            #pragma unroll
            for (int r = 0; r < 4; ++r) {
                const float* xp = inp + ((long)t * Bn + bbase + 16 * w + quad * 4 + r) * 3;
                xv[r][0] = xp[0]; xv[r][1] = xp[1]; xv[r][2] = xp[2];
            }
        }

        f32x4 acc[2][3];
        #pragma unroll
        for (int m = 0; m < 2; ++m)
            #pragma unroll
            for (int nt = 0; nt < 3; ++nt)
                acc[m][nt] = f32x4{0.f, 0.f, 0.f, 0.f};

        // ---- dataflow wait: THIS wave's K-slice (this ring) at MALL? ----
        // lane 0 spins, wave reconverges; volatile-asm ordering keeps the
        // h-burst loads below from hoisting above the poll. Target 16t:
        // 16 producer blocks bump once per step.
        if (lane == 0 && t) {
            const unsigned tgt = (unsigned)(t << 4);   // 16*t
            unsigned spins = 0;
            while (poll_read(&ctrl[GRP(R, leafC, w)]) < tgt) {
                __builtin_amdgcn_s_sleep(1);
                if (++spins > SPIN_LIMIT) break;   // watchdog
            }
        }

        // wave's A-frag base: frag f = 32w + 4*kki + 2R + m, at short-offset
        // f*512 + lane*8 (this ring's two mt stripes of the wave's kk range)
        const unsigned short* pa = hcur + ((long)(32 * w + 2 * R) * 64 + lane) * 8;

        // ---- ONE 16-load burst, counted-vmcnt split (R19) ----
        // issue order: hb[kki*2+m] -> hb[0..7] = kki 0..3, hb[8..15] = 4..7
        i32x4 hb[16];
        #pragma unroll
        for (int kki = 0; kki < 8; ++kki) {
            #pragma unroll
            for (int m = 0; m < 2; ++m) {
                asm volatile("global_load_dwordx4 %0, %1, off sc0 sc1"
                             : "=v"(hb[kki * 2 + m])
                             : "v"(pa + (long)(kki * 4 + m) * 512) : "memory");
            }
        }
        // wait for the 8 OLDEST (hb[0..7]); hb[8..15] stay in flight
        asm volatile("s_waitcnt vmcnt(8)"
                     : "+v"(hb[0]), "+v"(hb[1]), "+v"(hb[2]), "+v"(hb[3]),
                       "+v"(hb[4]), "+v"(hb[5]), "+v"(hb[6]), "+v"(hb[7])
                     :: "memory");
        __builtin_amdgcn_s_setprio(1);
        #pragma unroll
        for (int kki = 0; kki < 4; ++kki) {
            #pragma unroll
            for (int m = 0; m < 2; ++m) {
                union { i32x4 q; bf16x8 v; } u;
                u.q = hb[kki * 2 + m];
                bf16x8 a = u.v;
                acc[m][0] = __builtin_amdgcn_mfma_f32_16x16x32_bf16(a, Bf[0][kki], acc[m][0], 0, 0, 0);
                acc[m][1] = __builtin_amdgcn_mfma_f32_16x16x32_bf16(a, Bf[1][kki], acc[m][1], 0, 0, 0);
                acc[m][2] = __builtin_amdgcn_mfma_f32_16x16x32_bf16(a, Bf[2][kki], acc[m][2], 0, 0, 0);
            }
        }
        __builtin_amdgcn_s_setprio(0);
        // drain the remaining 8 (hb[8..15]) and finish
        asm volatile("s_waitcnt vmcnt(0)"
                     : "+v"(hb[8]), "+v"(hb[9]), "+v"(hb[10]), "+v"(hb[11]),
                       "+v"(hb[12]), "+v"(hb[13]), "+v"(hb[14]), "+v"(hb[15])
                     :: "memory");
        __builtin_amdgcn_s_setprio(1);
        #pragma unroll
        for (int kki = 4; kki < 8; ++kki) {
            #pragma unroll
            for (int m = 0; m < 2; ++m) {
                union { i32x4 q; bf16x8 v; } u;
                u.q = hb[kki * 2 + m];
                bf16x8 a = u.v;
                acc[m][0] = __builtin_amdgcn_mfma_f32_16x16x32_bf16(a, Bf[0][kki], acc[m][0], 0, 0, 0);
                acc[m][1] = __builtin_amdgcn_mfma_f32_16x16x32_bf16(a, Bf[1][kki], acc[m][1], 0, 0, 0);
                acc[m][2] = __builtin_amdgcn_mfma_f32_16x16x32_bf16(a, Bf[2][kki], acc[m][2], 0, 0, 0);
            }
        }
        __builtin_amdgcn_s_setprio(0);

        // ---- two-round cross-wave K reduction through LDS (24 KB) ----
        // Batched writes / batched reads with barriers between (R14 lesson:
        // merging read+writeback per-element serializes the LDS round-trips).
        if (w >= 4) {
            #pragma unroll
            for (int m = 0; m < 2; ++m)
                #pragma unroll
                for (int nt = 0; nt < 3; ++nt)
                    red[w - 4][m][nt][lane] = acc[m][nt];
        }
        __syncthreads();   // sync1
        if (w < 4) {
            #pragma unroll
            for (int m = 0; m < 2; ++m)
                #pragma unroll
                for (int nt = 0; nt < 3; ++nt)
                    acc[m][nt] += red[w][m][nt][lane];
        }
        __syncthreads();   // sync2
        if (w < 4) {
            #pragma unroll
            for (int m = 0; m < 2; ++m)
                #pragma unroll
                for (int nt = 0; nt < 3; ++nt)
                    red[w][m][nt][lane] = acc[m][nt];
        }
        __syncthreads();   // sync3

        if (w < 2) {
            f32x4 s0 = red[0][w][0][lane], s1 = red[0][w][1][lane], s2 = red[0][w][2][lane];
            #pragma unroll
            for (int src = 1; src < 4; ++src) {
                s0 += red[src][w][0][lane];
                s1 += red[src][w][1][lane];
                s2 += red[src][w][2][lane];
            }
            #pragma unroll
            for (int r = 0; r < 4; ++r) {
                const int b = bbase + 16 * w + quad * 4 + r;
                float pr = br_ + wr0*xv[r][0] + wr1*xv[r][1] + wr2*xv[r][2] + s0[r];
                float pz = bz_ + wz0*xv[r][0] + wz1*xv[r][1] + wz2*xv[r][2] + s1[r];
                float rr = sigm(pr);
                float zz = sigm(pz);
                float pn = bn2_ + wn0*xv[r][0] + wn1*xv[r][1] + wn2*xv[r][2] + rr * (s2[r] + bnn_);
                float nn = tanh_f(pn);
                float hv = nn + zz * (hst[r] - nn);
                hst[r] = hv;
                store_short_wt(hnext + ((long)((kkE * 4 + 2 * R + w) * 64) + qE * 16 + quad * 4 + r) * 8 + eE,
                               (unsigned)f2b(hv));
                if (c == 0 && n16 == 0)
                    store_dword_wt(out + t * Bn + b, hv);
            }
        }

        // ---- producer signal: drain WT stores, then bump all 16 leaf
        // replicas of our ring's group counter (16 lanes, one atomic instr,
        // 16 distinct lines -> no single-line arrival serialization) ----
        asm volatile("s_waitcnt vmcnt(0)" ::: "memory");  // belt-and-braces drain
        __syncthreads();   // sync4: all waves' stores at MALL; fences LDS reuse
        if (tid < 16)
            __hip_atomic_fetch_add(&ctrl[GRP(R, tid, grp)], 1u,
                                   __ATOMIC_RELAXED, __HIP_MEMORY_SCOPE_SYSTEM);
        // no loop-end barrier: sync4 already orders round-2 reads before any
        // next-iteration LDS write; waves 1-7 head straight into their polls.
    }
}

extern "C" void kernel_launch(void* const* d_in, const int* in_sizes, int n_in,
                              void* d_out, int out_size, void* d_ws, size_t ws_size,
                              hipStream_t stream) {
    const float* inp    = (const float*)d_in[0];  // [1024][64][3]
    const float* init_h = (const float*)d_in[1];  // [64][2048]
    const float* w_ih   = (const float*)d_in[2];  // [6144][3]
    const float* w_hh   = (const float*)d_in[3];  // [6144][2048]
    const float* bias   = (const float*)d_in[4];  // [6144]
    const float* bias_n = (const float*)d_in[5];  // [2048]
    float* out = (float*)d_out;                   // [1024][64]

    unsigned short* h0 = (unsigned short*)d_ws;          // 262144 B
    unsigned short* h1 = h0 + 131072L;                   // 262144 B
    unsigned* ctrl     = (unsigned*)(h1 + 131072L);      // 32768 B

    prep_kernel<<<128, 256, 0, stream>>>(init_h, h0, ctrl);
    gru_kernel<<<NBLK, NTHR, 0, stream>>>(inp, init_h, w_ih, w_hh, bias, bias_n,
                                          h0, h1, ctrl, out);
}

// Round 8
// 3835.574 us; speedup vs baseline: 2.5622x; 1.0728x over previous
//
#include <hip/hip_runtime.h>

typedef __attribute__((ext_vector_type(8))) short bf16x8;
typedef __attribute__((ext_vector_type(4))) float f32x4;
typedef __attribute__((ext_vector_type(4))) int i32x4;

#define Tn 1024
#define Bn 64
#define Hn 2048
#define NBLK 256
#define NTHR 512

// R16 geometry (PROVEN): TWO independent rings (batch rows never mix in a
// GRU). Ring R owns batch rows [32R, 32R+32); 128 col-blocks of 16 cols per
// ring. blockIdx.x -> R = bid & 1, c = bid >> 1.
//
// REGISTER WALL (R18 lesson): with 8-wave blocks (2 waves/SIMD), unified
// VGPR+AGPR budget is 256/wave. Bf regs = 3*cols*K_per_wave/128; at 16 cols
// -> 96 ✓; at 32 cols -> 192 -> scratch spill (WRITE_SIZE 2.1x, dur 2.26x).
// Col-blocks >16 need 4-wave/512-reg blocks -- deferred, high risk.
//
// Dataflow ready counters: one line per (ring, consumer-leaf, K-slice-group).
// 2 rings x 16 leaves x 8 groups = 256 counters, each on its own 128B line
// (32 KB ctrl). Replica (R, leaf, g) is bumped once per step by each of the
// 16 producer col-blocks of group g in ring R (c>>4 == g); value == 16*(t+1)
// means ring R's h_{t+1} slice g is fully at MALL. Consumers: wave w of
// col-block c polls (R, c>>3, w) -> 8 pollers/line (R12 lesson: >100 RMW
// pollers on ONE line serialize, so replicate per leaf).
#define GRP(ring, leaf, g) (((((ring) << 7) | ((leaf) << 3) | (g))) * 32)

// watchdog: bounded spin so a liveness bug degrades to a wrong answer
// (diagnosable absmax failure) instead of a container-killing hang
#define SPIN_LIMIT (1u << 25)

__device__ __forceinline__ unsigned short f2b(float x) {
    // fp32 -> bf16 round-to-nearest-even
    unsigned u = __float_as_uint(x);
    return (unsigned short)((u + 0x7fffu + ((u >> 16) & 1u)) >> 16);
}
__device__ __forceinline__ float sigm(float x) {
    return __builtin_amdgcn_rcpf(1.0f + __expf(-x));
}
__device__ __forceinline__ float tanh_f(float x) {
    float e = __expf(2.0f * x);
    return 1.0f - 2.0f * __builtin_amdgcn_rcpf(1.0f + e);
}

// write-through system-scope stores: at MALL once vmcnt retires
__device__ __forceinline__ void store_short_wt(unsigned short* p, unsigned v) {
    asm volatile("global_store_short %0, %1, off sc0 sc1" :: "v"(p), "v"(v) : "memory");
}
__device__ __forceinline__ void store_dword_wt(float* p, float v) {
    asm volatile("global_store_dword %0, %1, off sc0 sc1" :: "v"(p), "v"(__float_as_uint(v)) : "memory");
}
__device__ __forceinline__ void store_u64_wt(unsigned long long* p, unsigned long long v) {
    asm volatile("global_store_dwordx2 %0, %1, off sc0 sc1" :: "v"(p), "v"(v) : "memory");
}
// Poll via atomic RMW(+0): the ONLY read primitive proven promptly coherent
// cross-XCD for ATOMICALLY-updated lines (R1-R6 ablation). asm because
// InstCombine turns fetch_add(p,0) back into a plain atomic load.
__device__ __forceinline__ unsigned poll_read(unsigned* p) {
    unsigned old;
    asm volatile("global_atomic_add %0, %1, %2, off sc0 sc1\n\ts_waitcnt vmcnt(0)"
                 : "=v"(old) : "v"(p), "v"(0u) : "memory");
    return old;
}

// h fragment layout (GLOBAL, shared by both rings; each ring touches only its
// own mt stripes): h_f[kk][mt][laneF][e], kk=k>>5, mt=b>>4,
// laneF=((k>>3)&3)*16+(b&15), e=k&7. One MFMA A-frag = 64 lanes x 16B contig.
__device__ __forceinline__ long hfrag_off(int b, int k) {
    return ((long)(((k >> 5) * 4 + (b >> 4)) * 64) + ((k >> 3) & 3) * 16 + (b & 15)) * 8 + (k & 7);
}

// Prep: init_hidden fp32 -> bf16 h0 (frag layout, WT stores so the MALL copy
// is authoritative for gru's bypass loads); zero ready counters (WT too).
__global__ void prep_kernel(const float* __restrict__ init_h,
                            unsigned short* __restrict__ h0,
                            unsigned* __restrict__ ctrl) {
    const int i = blockIdx.x * 256 + threadIdx.x;  // 0..32767
    const int b  = i >> 9;
    const int k4 = (i & 511) << 2;
    float4 v = *reinterpret_cast<const float4*>(init_h + (long)b * Hn + k4);
    unsigned long long q = (unsigned long long)f2b(v.x)
                         | ((unsigned long long)f2b(v.y) << 16)
                         | ((unsigned long long)f2b(v.z) << 32)
                         | ((unsigned long long)f2b(v.w) << 48);
    store_u64_wt((unsigned long long*)(h0 + hfrag_off(b, k4)), q);
    if (i < 8192)
        asm volatile("global_store_dword %0, %1, off sc0 sc1"
                     :: "v"(ctrl + i), "v"(0u) : "memory");
}

// Persistent GRU. 256 blocks x 512 threads (8 waves) = 1 block/CU, all CUs.
// Ring R (bid&1) owns batch rows [32R,32R+32); col-block c (bid>>1) owns 16
// hidden units j in [16c, 16c+16). Wave w owns K-slice [256w, 256w+256);
// W rows live in REGISTERS (Bf[3][8] = 96 VGPRs).
//
// Ledger: R13 dataflow flags (-11%). R14 REVERTED (x loads stay BEFORE the
//   poll; LDS ops stay BATCHED). R15 setprio null (kept). R16 2-ring split +
//   single 16-load burst (-23%, 4337). R17 parity/2-barrier/per-wave-bump:
//   null -> reverted. R18 32-col: register wall, REVERTED. R19 counted-vmcnt
//   2-way split (-5%, 4115): load phase HAS exposed latency -> extend.
// R20 (this):
//   (1) 4-way vmcnt ladder (12/8/4/0): all 16 loads issue back-to-back
//       (full MLP); each counted wait releases 4 frags for 12 MFMAs while
//       the rest stay in flight. t=0 safety: a counted wait of N leaves the
//       N NEWEST VMEM ops outstanding; everything older (pre-poll x loads,
//       earlier hb's) has retired -> released frags always valid (m135
//       issue-order retirement, same argument as R19's vmcnt(8)).
//   (2) SINGLE-ROUND reduce: 8 waves write 8 disjoint buckets (48 KB, within
//       the proven <=64KB static-LDS limit), ONE barrier, epilogue waves 0-1
//       sum all 8 buckets (24 batched ds_read_b128 -- batched per R14).
//       Deletes sync2+sync3 and the round-2 LDS write round. Barriers/wave/
//       iter: uniform 2 (sync1, sync4).
//
// Buffer-reuse safety: a block stores h_{t+2} only after its 8 waves saw all
// counters at 16(t+1), i.e. after EVERY producer of its ring stored h_{t+1},
// which (program order + drain) is after those blocks finished READING h_t
// -> the double buffer never races. Skew < 2 steps, deadlock-free (all 256
// blocks co-resident: 1 block/CU, 48KB LDS, 8 waves, 128 VGPR).
//
// NO fences / cache maintenance in the hot loop (R5). All signals via RMW,
// all polls via RMW(+0).
__global__ void __launch_bounds__(NTHR, 2) gru_kernel(
    const float* __restrict__ inp,     // [T][B][3]
    const float* __restrict__ init_h,  // [B][H]
    const float* __restrict__ w_ih,    // [3H][3]
    const float* __restrict__ w_hh,    // [3H][H] fp32
    const float* __restrict__ bias,    // [3H]
    const float* __restrict__ bias_n,  // [H]
    unsigned short* __restrict__ h0,   // [B][H] bf16 frag-layout double buffer
    unsigned short* __restrict__ h1,
    unsigned* __restrict__ ctrl,       // [8192] ready counters (256 lines)
    float* __restrict__ out)           // [T][B]
{
    __shared__ f32x4 red[8][2][3][64];  // [bucket][m][nt][lane] = 48 KB

    const int tid  = threadIdx.x;
    const int lane = tid & 63;
    const int w    = tid >> 6;      // wave id = K-slice owner
    const int quad = lane >> 4;
    const int n16  = lane & 15;
    const int R    = blockIdx.x & 1;        // ring id (batch half)
    const int c    = blockIdx.x >> 1;       // col-block id 0..127
    const int jg   = c * 16 + n16;  // this lane's hidden column (epilogue)
    const int ks   = w * 256;
    const int bbase = 32 * R;       // ring's batch base

    // ---- preload W rows into registers as bf16 B-fragments (one-time) ----
    bf16x8 Bf[3][8];
    #pragma unroll
    for (int nt = 0; nt < 3; ++nt) {
        const long row = (long)(nt * Hn + jg);
        #pragma unroll
        for (int k = 0; k < 8; ++k) {
            const float* p = w_hh + row * Hn + ks + k * 32 + quad * 8;
            bf16x8 b;
            #pragma unroll
            for (int j = 0; j < 8; ++j) b[j] = (short)f2b(p[j]);
            Bf[nt][k] = b;
        }
    }

    // Epilogue constants (used by waves 0-1; all 64 lanes active)
    float wr0 = w_ih[jg*3+0], wr1 = w_ih[jg*3+1], wr2 = w_ih[jg*3+2];
    float wz0 = w_ih[(Hn+jg)*3+0], wz1 = w_ih[(Hn+jg)*3+1], wz2 = w_ih[(Hn+jg)*3+2];
    float wn0 = w_ih[(2*Hn+jg)*3+0], wn1 = w_ih[(2*Hn+jg)*3+1], wn2 = w_ih[(2*Hn+jg)*3+2];
    float br_ = bias[jg], bz_ = bias[Hn+jg], bn2_ = bias[2*Hn+jg];
    float bnn_ = bias_n[jg];

    // fp32 hidden state (waves 0-1; batch b = bbase + 16w + quad*4 + r, col jg)
    float hst[4];
    if (w < 2) {
        #pragma unroll
        for (int r = 0; r < 4; ++r)
            hst[r] = init_h[(long)(bbase + 16 * w + quad * 4 + r) * Hn + jg];
    }

    // epilogue frag-store decomposition of j = 16c + n16 (mt = 2R + w)
    const int kkE = c >> 1;                     // j>>5 (lane-uniform)
    const int qE  = (c & 1) * 2 + (n16 >> 3);
    const int eE  = n16 & 7;

    const int leafC = c >> 3;          // consumer replica index (per ring)
    const int grp   = c >> 4;          // K-slice group we produce (per ring)

    for (int t = 0; t < Tn; ++t) {
        const unsigned short* hcur = (t & 1) ? h1 : h0;
        unsigned short* hnext      = (t & 1) ? h0 : h1;

        // input contributions for this step. Issued BEFORE the poll: their
        // HBM/MALL RTT hides entirely under the poll's own atomic RTT
        // (R14 lesson: any other placement puts them on the critical path).
        float xv[4][3];
        if (w < 2) {
            #pragma unroll
            for (int r = 0; r < 4; ++r) {
                const float* xp = inp + ((long)t * Bn + bbase + 16 * w + quad * 4 + r) * 3;
                xv[r][0] = xp[0]; xv[r][1] = xp[1]; xv[r][2] = xp[2];
            }
        }

        f32x4 acc[2][3];
        #pragma unroll
        for (int m = 0; m < 2; ++m)
            #pragma unroll
            for (int nt = 0; nt < 3; ++nt)
                acc[m][nt] = f32x4{0.f, 0.f, 0.f, 0.f};

        // ---- dataflow wait: THIS wave's K-slice (this ring) at MALL? ----
        // lane 0 spins, wave reconverges; volatile-asm ordering keeps the
        // h-burst loads below from hoisting above the poll. Target 16t:
        // 16 producer blocks bump once per step.
        if (lane == 0 && t) {
            const unsigned tgt = (unsigned)(t << 4);   // 16*t
            unsigned spins = 0;
            while (poll_read(&ctrl[GRP(R, leafC, w)]) < tgt) {
                __builtin_amdgcn_s_sleep(1);
                if (++spins > SPIN_LIMIT) break;   // watchdog
            }
        }

        // wave's A-frag base: frag f = 32w + 4*kki + 2R + m, at short-offset
        // f*512 + lane*8 (this ring's two mt stripes of the wave's kk range)
        const unsigned short* pa = hcur + ((long)(32 * w + 2 * R) * 64 + lane) * 8;

        // ---- ONE 16-load burst, 4-way counted-vmcnt ladder (R20) ----
        // issue order: hb[kki*2+m] -> quarters {0..3},{4..7},{8..11},{12..15}
        i32x4 hb[16];
        #pragma unroll
        for (int kki = 0; kki < 8; ++kki) {
            #pragma unroll
            for (int m = 0; m < 2; ++m) {
                asm volatile("global_load_dwordx4 %0, %1, off sc0 sc1"
                             : "=v"(hb[kki * 2 + m])
                             : "v"(pa + (long)(kki * 4 + m) * 512) : "memory");
            }
        }
        // Q0: <=12 outstanding -> hb[0..3] (and all older x loads) retired
        asm volatile("s_waitcnt vmcnt(12)"
                     : "+v"(hb[0]), "+v"(hb[1]), "+v"(hb[2]), "+v"(hb[3])
                     :: "memory");
        __builtin_amdgcn_s_setprio(1);
        #pragma unroll
        for (int kki = 0; kki < 2; ++kki) {
            #pragma unroll
            for (int m = 0; m < 2; ++m) {
                union { i32x4 q; bf16x8 v; } u;
                u.q = hb[kki * 2 + m];
                bf16x8 a = u.v;
                acc[m][0] = __builtin_amdgcn_mfma_f32_16x16x32_bf16(a, Bf[0][kki], acc[m][0], 0, 0, 0);
                acc[m][1] = __builtin_amdgcn_mfma_f32_16x16x32_bf16(a, Bf[1][kki], acc[m][1], 0, 0, 0);
                acc[m][2] = __builtin_amdgcn_mfma_f32_16x16x32_bf16(a, Bf[2][kki], acc[m][2], 0, 0, 0);
            }
        }
        __builtin_amdgcn_s_setprio(0);
        // Q1
        asm volatile("s_waitcnt vmcnt(8)"
                     : "+v"(hb[4]), "+v"(hb[5]), "+v"(hb[6]), "+v"(hb[7])
                     :: "memory");
        __builtin_amdgcn_s_setprio(1);
        #pragma unroll
        for (int kki = 2; kki < 4; ++kki) {
            #pragma unroll
            for (int m = 0; m < 2; ++m) {
                union { i32x4 q; bf16x8 v; } u;
                u.q = hb[kki * 2 + m];
                bf16x8 a = u.v;
                acc[m][0] = __builtin_amdgcn_mfma_f32_16x16x32_bf16(a, Bf[0][kki], acc[m][0], 0, 0, 0);
                acc[m][1] = __builtin_amdgcn_mfma_f32_16x16x32_bf16(a, Bf[1][kki], acc[m][1], 0, 0, 0);
                acc[m][2] = __builtin_amdgcn_mfma_f32_16x16x32_bf16(a, Bf[2][kki], acc[m][2], 0, 0, 0);
            }
        }
        __builtin_amdgcn_s_setprio(0);
        // Q2
        asm volatile("s_waitcnt vmcnt(4)"
                     : "+v"(hb[8]), "+v"(hb[9]), "+v"(hb[10]), "+v"(hb[11])
                     :: "memory");
        __builtin_amdgcn_s_setprio(1);
        #pragma unroll
        for (int kki = 4; kki < 6; ++kki) {
            #pragma unroll
            for (int m = 0; m < 2; ++m) {
                union { i32x4 q; bf16x8 v; } u;
                u.q = hb[kki * 2 + m];
                bf16x8 a = u.v;
                acc[m][0] = __builtin_amdgcn_mfma_f32_16x16x32_bf16(a, Bf[0][kki], acc[m][0], 0, 0, 0);
                acc[m][1] = __builtin_amdgcn_mfma_f32_16x16x32_bf16(a, Bf[1][kki], acc[m][1], 0, 0, 0);
                acc[m][2] = __builtin_amdgcn_mfma_f32_16x16x32_bf16(a, Bf[2][kki], acc[m][2], 0, 0, 0);
            }
        }
        __builtin_amdgcn_s_setprio(0);
        // Q3
        asm volatile("s_waitcnt vmcnt(0)"
                     : "+v"(hb[12]), "+v"(hb[13]), "+v"(hb[14]), "+v"(hb[15])
                     :: "memory");
        __builtin_amdgcn_s_setprio(1);
        #pragma unroll
        for (int kki = 6; kki < 8; ++kki) {
            #pragma unroll
            for (int m = 0; m < 2; ++m) {
                union { i32x4 q; bf16x8 v; } u;
                u.q = hb[kki * 2 + m];
                bf16x8 a = u.v;
                acc[m][0] = __builtin_amdgcn_mfma_f32_16x16x32_bf16(a, Bf[0][kki], acc[m][0], 0, 0, 0);
                acc[m][1] = __builtin_amdgcn_mfma_f32_16x16x32_bf16(a, Bf[1][kki], acc[m][1], 0, 0, 0);
                acc[m][2] = __builtin_amdgcn_mfma_f32_16x16x32_bf16(a, Bf[2][kki], acc[m][2], 0, 0, 0);
            }
        }
        __builtin_amdgcn_s_setprio(0);

        // ---- SINGLE-ROUND cross-wave K reduction through LDS (48 KB) ----
        // All 8 waves write their partials to disjoint buckets (batched).
        #pragma unroll
        for (int m = 0; m < 2; ++m)
            #pragma unroll
            for (int nt = 0; nt < 3; ++nt)
                red[w][m][nt][lane] = acc[m][nt];
        __syncthreads();   // sync1

        if (w < 2) {
            // 24 batched ds_read_b128 + 21 vector adds (R14: batched, never
            // per-element interleaved with writes)
            f32x4 s0 = red[0][w][0][lane], s1 = red[0][w][1][lane], s2 = red[0][w][2][lane];
            #pragma unroll
            for (int src = 1; src < 8; ++src) {
                s0 += red[src][w][0][lane];
                s1 += red[src][w][1][lane];
                s2 += red[src][w][2][lane];
            }
            #pragma unroll
            for (int r = 0; r < 4; ++r) {
                const int b = bbase + 16 * w + quad * 4 + r;
                float pr = br_ + wr0*xv[r][0] + wr1*xv[r][1] + wr2*xv[r][2] + s0[r];
                float pz = bz_ + wz0*xv[r][0] + wz1*xv[r][1] + wz2*xv[r][2] + s1[r];
                float rr = sigm(pr);
                float zz = sigm(pz);
                float pn = bn2_ + wn0*xv[r][0] + wn1*xv[r][1] + wn2*xv[r][2] + rr * (s2[r] + bnn_);
                float nn = tanh_f(pn);
                float hv = nn + zz * (hst[r] - nn);
                hst[r] = hv;
                store_short_wt(hnext + ((long)((kkE * 4 + 2 * R + w) * 64) + qE * 16 + quad * 4 + r) * 8 + eE,
                               (unsigned)f2b(hv));
                if (c == 0 && n16 == 0)
                    store_dword_wt(out + t * Bn + b, hv);
            }
        }

        // ---- producer signal: drain WT stores, then bump all 16 leaf
        // replicas of our ring's group counter (16 lanes, one atomic instr,
        // 16 distinct lines -> no single-line arrival serialization) ----
        asm volatile("s_waitcnt vmcnt(0)" ::: "memory");  // belt-and-braces drain
        __syncthreads();   // sync4: stores at MALL; also the red[] WAR fence
        if (tid < 16)
            __hip_atomic_fetch_add(&ctrl[GRP(R, tid, grp)], 1u,
                                   __ATOMIC_RELAXED, __HIP_MEMORY_SCOPE_SYSTEM);
        // no loop-end barrier: sync4 already orders epilogue LDS reads before
        // any next-iteration bucket write; waves 1-7 head straight into
        // their polls.
    }
}

extern "C" void kernel_launch(void* const* d_in, const int* in_sizes, int n_in,
                              void* d_out, int out_size, void* d_ws, size_t ws_size,
                              hipStream_t stream) {
    const float* inp    = (const float*)d_in[0];  // [1024][64][3]
    const float* init_h = (const float*)d_in[1];  // [64][2048]
    const float* w_ih   = (const float*)d_in[2];  // [6144][3]
    const float* w_hh   = (const float*)d_in[3];  // [6144][2048]
    const float* bias   = (const float*)d_in[4];  // [6144]
    const float* bias_n = (const float*)d_in[5];  // [2048]
    float* out = (float*)d_out;                   // [1024][64]

    unsigned short* h0 = (unsigned short*)d_ws;          // 262144 B
    unsigned short* h1 = h0 + 131072L;                   // 262144 B
    unsigned* ctrl     = (unsigned*)(h1 + 131072L);      // 32768 B

    prep_kernel<<<128, 256, 0, stream>>>(init_h, h0, ctrl);
    gru_kernel<<<NBLK, NTHR, 0, stream>>>(inp, init_h, w_ih, w_hh, bias, bias_n,
                                          h0, h1, ctrl, out);
}